// Round 8
// baseline (1759.745 us; speedup 1.0000x reference)
//
#include <hip/hip_runtime.h>
#include <math.h>

// Problem constants
#define NN 50000      // nodes
#define NE 800000     // edges
#define HD 512        // hidden
#define GN_EPS 1e-5f
#define NBCHUNK 196   // ceil(NN/256) for scan
#define GRIDM 391     // ceil(NN/128) GEMM grid rows
#define NGEMM (GRIDM*4)
#define PROPB 12500   // ceil(NN/4) prop blocks (4 nodes/block, 1 wave each)
#define STATS_NB 512  // combine1 stats partial blocks

typedef __attribute__((ext_vector_type(4))) float f4;
typedef __attribute__((ext_vector_type(4))) float f32x4;
typedef __attribute__((ext_vector_type(8))) short short8;
typedef unsigned short u16;
typedef __attribute__((ext_vector_type(4))) unsigned short us4;
typedef __attribute__((ext_vector_type(8))) unsigned short us8;

typedef struct { int s; float w; } edge_t;   // packed (src, norm) 8B

static __device__ __forceinline__ float elu1(float v){ return v > 0.f ? v : expm1f(v); }

static __device__ __forceinline__ float bf2f(u16 u){
  union { unsigned int i; float f; } v; v.i = ((unsigned int)u) << 16; return v.f;
}
static __device__ __forceinline__ u16 f2bf(float f){
  union { float f; unsigned int i; } v; v.f = f;
  unsigned int b = v.i;
  b += 0x7FFFu + ((b >> 16) & 1u);   // round-to-nearest-even
  return (u16)(b >> 16);
}

// LDS address for [row][128B] tiles: XOR the 16B-slot index with (row&7).
// Applied on BOTH stage-write and frag-read (reg-staged) -> 2 lanes/bank = conflict-free.
static __device__ __forceinline__ int lds_addr(int row, int chunkByte){
  return row*128 + (chunkByte ^ ((row & 7) << 4));
}

// ---------------- CSR build ----------------
__global__ void k_deg(const int* __restrict__ dst, const float* __restrict__ w,
                      float* __restrict__ deg, int* __restrict__ cnt) {
  int e = blockIdx.x*256 + threadIdx.x;
  if (e < NE) {
    int d = dst[e];
    atomicAdd(&deg[d], w[e]);
    atomicAdd(&cnt[d], 1);
  }
}

__global__ void k_dinv(float* __restrict__ deg) {
  int n = blockIdx.x*256 + threadIdx.x;
  if (n < NN) { float d = deg[n]; deg[n] = d > 0.f ? rsqrtf(d) : 0.f; }
}

// hierarchical scan: chunk-local inclusive -> chunk totals
__global__ void __launch_bounds__(256) k_scanA(const int* __restrict__ cnt,
                                               int* __restrict__ row_ptr,
                                               int* __restrict__ btot) {
  __shared__ int sh[256];
  int t = threadIdx.x, b = blockIdx.x;
  int i = b*256 + t;
  int v = (i < NN) ? cnt[i] : 0;
  sh[t] = v; __syncthreads();
  #pragma unroll
  for (int off = 1; off < 256; off <<= 1) {
    int x = (t >= off) ? sh[t-off] : 0;
    __syncthreads();
    sh[t] += x;
    __syncthreads();
  }
  if (i < NN) row_ptr[i+1] = sh[t];
  if (t == 255) btot[b] = sh[255];
}

__global__ void __launch_bounds__(256) k_scanB(const int* __restrict__ btot,
                                               int* __restrict__ boff) {
  __shared__ int sh[256];
  int t = threadIdx.x;
  int v = (t < NBCHUNK) ? btot[t] : 0;
  sh[t] = v; __syncthreads();
  #pragma unroll
  for (int off = 1; off < 256; off <<= 1) {
    int x = (t >= off) ? sh[t-off] : 0;
    __syncthreads();
    sh[t] += x;
    __syncthreads();
  }
  if (t < NBCHUNK) boff[t] = sh[t] - v;   // exclusive
}

__global__ void __launch_bounds__(256) k_scanC(int* __restrict__ row_ptr,
                                               const int* __restrict__ boff) {
  int t = threadIdx.x, b = blockIdx.x;
  int i = b*256 + t;
  if (i < NN) row_ptr[i+1] += boff[b];
  if (i == 0) row_ptr[0] = 0;
}

__global__ void k_fill(const int* __restrict__ src, const int* __restrict__ dst,
                       const float* __restrict__ w, const float* __restrict__ dinv,
                       const int* __restrict__ row_ptr, int* __restrict__ cursor,
                       edge_t* __restrict__ edges) {
  int e = blockIdx.x*256 + threadIdx.x;
  if (e < NE) {
    int s = src[e], d = dst[e];
    int pos = atomicAdd(&cursor[d], 1);
    int idx = row_ptr[d] + pos;
    edge_t ed; ed.s = s; ed.w = dinv[s] * w[e] * dinv[d];
    edges[idx] = ed;
  }
}

// ---------------- width-4 propagation (layers 1 & 3), all f32 ----------------
__global__ void k_prop4(const int* __restrict__ row_ptr, const edge_t* __restrict__ edges,
                        const f4* __restrict__ in1, const f4* __restrict__ in2,
                        const f4* __restrict__ base, const float* __restrict__ bias,
                        f4* __restrict__ out) {
  int n = blockIdx.x*256 + threadIdx.x;
  if (n >= NN) return;
  f4 acc = {0.f,0.f,0.f,0.f};
  int e0 = row_ptr[n], e1 = row_ptr[n+1];
  if (in2) {
    for (int e = e0; e < e1; ++e) {
      edge_t ed = edges[e];
      acc += ed.w * (in1[ed.s] + in2[ed.s]);
    }
  } else {
    for (int e = e0; e < e1; ++e) {
      edge_t ed = edges[e];
      acc += ed.w * in1[ed.s];
    }
  }
  if (base) acc += base[n];
  if (bias) { acc[0]+=bias[0]; acc[1]+=bias[1]; acc[2]+=bias[2]; acc[3]+=bias[3]; }
  out[n] = acc;
}

// ---------------- layer-1 combine fused with stats: bf16 out + column partials ----------------
__global__ void __launch_bounds__(256) k_combine1s(
    const f4* __restrict__ x, const f4* __restrict__ h1, const f4* __restrict__ h2,
    const f4* __restrict__ h3, const float* __restrict__ W1, const float* __restrict__ b1,
    u16* __restrict__ act, float* __restrict__ pS, float* __restrict__ pQ) {
  __shared__ float sdS[HD], sdQ[HD];
  int t = threadIdx.x;
  int half = t >> 7;
  int c4 = (t & 127) * 4;
  f4 wcol[16];
  #pragma unroll
  for (int kf = 0; kf < 16; ++kf)
    wcol[kf] = *reinterpret_cast<const f4*>(W1 + (size_t)kf*HD + c4);
  f4 bv = *reinterpret_cast<const f4*>(b1 + c4);
  f4 s = {0.f,0.f,0.f,0.f}, qq = {0.f,0.f,0.f,0.f};
  for (int n = blockIdx.x*2 + half; n < NN; n += gridDim.x*2) {
    f4 hv0 = x[n], hv1 = h1[n], hv2 = h2[n], hv3 = h3[n];
    f4 acc = bv;
    #pragma unroll
    for (int f = 0; f < 4; ++f) acc += hv0[f] * wcol[f];
    #pragma unroll
    for (int f = 0; f < 4; ++f) acc += hv1[f] * wcol[4+f];
    #pragma unroll
    for (int f = 0; f < 4; ++f) acc += hv2[f] * wcol[8+f];
    #pragma unroll
    for (int f = 0; f < 4; ++f) acc += hv3[f] * wcol[12+f];
    us4 o;
    #pragma unroll
    for (int e = 0; e < 4; ++e) {
      float v = elu1(acc[e]);
      s[e] += v; qq[e] += v*v;
      o[e] = f2bf(v);
    }
    *reinterpret_cast<us4*>(act + (size_t)n*HD + c4) = o;
  }
  if (half) {
    *reinterpret_cast<f4*>(&sdS[c4]) = s;
    *reinterpret_cast<f4*>(&sdQ[c4]) = qq;
  }
  __syncthreads();
  if (!half) {
    f4 ts = *reinterpret_cast<f4*>(&sdS[c4]) + s;
    f4 tq = *reinterpret_cast<f4*>(&sdQ[c4]) + qq;
    *reinterpret_cast<f4*>(&pS[(size_t)blockIdx.x*HD + c4]) = ts;
    *reinterpret_cast<f4*>(&pQ[(size_t)blockIdx.x*HD + c4]) = tq;
  }
}

// ---------------- reduce partials [nb][512] -> s1,s2 ----------------
__global__ void __launch_bounds__(256) k_reduce(
    const float* __restrict__ pS, const float* __restrict__ pQ, int nb,
    float* __restrict__ s1, float* __restrict__ s2) {
  int c = blockIdx.x*256 + threadIdx.x;
  if (c >= HD) return;
  float a = 0.f, b = 0.f;
  for (int i = 0; i < nb; ++i) {
    a += pS[(size_t)i*HD + c];
    b += pQ[(size_t)i*HD + c];
  }
  s1[c] = a; s2[c] = b;
}

// ---------------- GraphNorm scale/shift precompute: v_norm = sc*v + sh ----------------
__global__ void k_affine(const float* __restrict__ s1, const float* __restrict__ s2,
                         const float* __restrict__ gw, const float* __restrict__ gb,
                         const float* __restrict__ ga,
                         float* __restrict__ sc, float* __restrict__ sh) {
  int c = blockIdx.x*256 + threadIdx.x;
  if (c >= HD) return;
  float mu = s1[c]*(1.f/NN);
  float a  = ga[c];
  float var = s2[c]*(1.f/NN) - 2.f*a*mu*mu + a*a*mu*mu;
  float inv = rsqrtf(var + GN_EPS);
  sc[c] = gw[c]*inv;
  sh[c] = gb[c] - gw[c]*inv*a*mu;
}

// ---------------- in-place bf16 normalize with precomputed sc/sh ----------------
__global__ void k_norm_ip(u16* __restrict__ buf, const float* __restrict__ sc,
                          const float* __restrict__ sh) {
  size_t i = (size_t)blockIdx.x*256 + threadIdx.x;
  size_t total = (size_t)NN*HD/8;
  if (i >= total) return;
  int c = (int)((i*8) % HD);
  us8 v = reinterpret_cast<us8*>(buf)[i];
  #pragma unroll
  for (int e = 0; e < 8; ++e) v[e] = f2bf(bf2f(v[e])*sc[c+e] + sh[c+e]);
  reinterpret_cast<us8*>(buf)[i] = v;
}

// ---------------- W2 -> bf16 transposed: Bt[k][out][in] = bf16(W2[k][in][out]) ----------------
__global__ void k_w2t(const float* __restrict__ W2, u16* __restrict__ Bt) {
  size_t idx = (size_t)blockIdx.x*256 + threadIdx.x;
  if (idx >= (size_t)4*HD*HD) return;
  int i = (int)(idx & 511);          // in  (fastest -> coalesced write)
  int o = (int)((idx >> 9) & 511);   // out
  int k = (int)(idx >> 18);
  Bt[idx] = f2bf(W2[((size_t)k*HD + i)*HD + o]);
}

// ---------------- fat kernel: [GEMM blocks | prop blocks] in one dispatch ----------------
// GEMM: Cbf (+)= A[M,512] @ Bt^T (K=512). Reg-staged + prefetch, both-side swizzle.
// PROP: pout[n] = sum_e w_e * pin[src_e]  (width-512 bf16 gather), block-role split.
// ACC: accumulate into Cbf. FINAL: v=elu(C+acc+bias), store, per-channel stats.
#define BM 128
#define BN 128
#define BKS 64
template<int ACC, int FINAL, int PROP>
__global__ void __launch_bounds__(256) k_fat(
    const u16* __restrict__ A, const u16* __restrict__ Bt,
    u16* __restrict__ Cbf, const float* __restrict__ bias,
    float* __restrict__ pS, float* __restrict__ pQ,
    const int* __restrict__ row_ptr, const edge_t* __restrict__ edges,
    const u16* __restrict__ pin, u16* __restrict__ pout, int M) {
  __shared__ u16 As[BM*BKS];   // 16 KB (swizzled content)
  __shared__ u16 Bs[BN*BKS];   // 16 KB
  __shared__ float sdS[FINAL ? BN : 1], sdQ[FINAL ? BN : 1];
  int t = threadIdx.x;

  if (PROP && blockIdx.x >= NGEMM) {
    // ---- propagation role ----
    int wv = t >> 6;
    int l  = t & 63;
    int n = (blockIdx.x - NGEMM)*4 + wv;
    if (n >= NN) return;
    int e0 = row_ptr[n], e1 = row_ptr[n+1];
    float acc[8] = {0.f,0.f,0.f,0.f,0.f,0.f,0.f,0.f};
    const u16* basep = pin + l*8;
    for (int e = e0; e < e1; ++e) {
      edge_t ed = edges[e];
      us8 v = *reinterpret_cast<const us8*>(basep + (size_t)ed.s*HD);
      #pragma unroll
      for (int q = 0; q < 8; ++q) acc[q] += ed.w * bf2f(v[q]);
    }
    us8 o;
    #pragma unroll
    for (int q = 0; q < 8; ++q) o[q] = f2bf(acc[q]);
    *reinterpret_cast<us8*>(pout + (size_t)n*HD + l*8) = o;
    return;
  }

  // ---- GEMM role ----
  // XCD-bijective remap (m204) over the NGEMM sub-grid, col-fastest
  const int nwg = NGEMM;
  int q = nwg >> 3, r = nwg & 7;
  int xcd = blockIdx.x & 7, sub = blockIdx.x >> 3;
  int nid = (xcd < r ? xcd*(q+1) : r*(q+1) + (xcd - r)*q) + sub;
  int bmi = nid >> 2;             // row-panel index (0..GRIDM-1)
  int bni = nid & 3;              // col-panel index (0..3)
  int bm = bmi * BM, bn = bni * BN;

  int w  = t >> 6;
  int l  = t & 63;
  int wr = (w >> 1) * 64;
  int wc = (w & 1) * 64;
  int lr = l & 15;
  int lq = l >> 4;

  if (FINAL && t < BN) { sdS[t] = 0.f; sdQ[t] = 0.f; }

  // staging map: 4 slots/thread; slot s -> row = s>>3, 16B-chunk c8 = s&7
  size_t aoffs[4], boffs[4];
  int wb[4];
  #pragma unroll
  for (int p2 = 0; p2 < 4; ++p2) {
    int s = p2*256 + t;
    int row = s >> 3, c8 = s & 7;
    int ga = bm + row; if (ga >= M) ga = M - 1;
    aoffs[p2] = (size_t)ga*HD + c8*8;
    boffs[p2] = (size_t)(bn + row)*HD + c8*8;
    wb[p2] = lds_addr(row, c8*16);
  }

  f32x4 acc[4][4];
  #pragma unroll
  for (int i = 0; i < 4; ++i)
    #pragma unroll
    for (int j = 0; j < 4; ++j) acc[i][j] = (f32x4){0.f,0.f,0.f,0.f};

  us8 ra[4], rb[4];
  #pragma unroll
  for (int p2 = 0; p2 < 4; ++p2) {
    ra[p2] = *reinterpret_cast<const us8*>(A + aoffs[p2]);
    rb[p2] = *reinterpret_cast<const us8*>(Bt + boffs[p2]);
  }

  for (int h = 0; h < 8; ++h) {
    __syncthreads();   // previous tile's LDS reads complete
    #pragma unroll
    for (int p2 = 0; p2 < 4; ++p2) {
      *reinterpret_cast<us8*>((char*)As + wb[p2]) = ra[p2];
      *reinterpret_cast<us8*>((char*)Bs + wb[p2]) = rb[p2];
    }
    if (h < 7) {       // prefetch next K-tile (overlaps MFMA below)
      int off = (h+1)*BKS;
      #pragma unroll
      for (int p2 = 0; p2 < 4; ++p2) {
        ra[p2] = *reinterpret_cast<const us8*>(A + aoffs[p2] + off);
        rb[p2] = *reinterpret_cast<const us8*>(Bt + boffs[p2] + off);
      }
    }
    __syncthreads();   // tile ready
    #pragma unroll
    for (int ks = 0; ks < 2; ++ks) {
      short8 af[4], bfr[4];
      #pragma unroll
      for (int mi = 0; mi < 4; ++mi)
        af[mi] = *reinterpret_cast<const short8*>(
            (char*)As + lds_addr(wr + mi*16 + lr, ks*64 + lq*16));
      #pragma unroll
      for (int ni = 0; ni < 4; ++ni)
        bfr[ni] = *reinterpret_cast<const short8*>(
            (char*)Bs + lds_addr(wc + ni*16 + lr, ks*64 + lq*16));
      #pragma unroll
      for (int mi = 0; mi < 4; ++mi)
        #pragma unroll
        for (int ni = 0; ni < 4; ++ni)
          acc[mi][ni] = __builtin_amdgcn_mfma_f32_16x16x32_bf16(af[mi], bfr[ni], acc[mi][ni], 0, 0, 0);
    }
  }

  if (!FINAL) {
    #pragma unroll
    for (int mi = 0; mi < 4; ++mi)
      #pragma unroll
      for (int ni = 0; ni < 4; ++ni)
        #pragma unroll
        for (int rr = 0; rr < 4; ++rr) {
          int gm = bm + wr + mi*16 + lq*4 + rr;
          int gn = bn + wc + ni*16 + lr;
          if (gm < M) {
            u16* cp = &Cbf[(size_t)gm*HD + gn];
            float v = acc[mi][ni][rr];
            if (ACC) v += bf2f(*cp);
            *cp = f2bf(v);
          }
        }
  } else {
    float psum[4] = {0.f,0.f,0.f,0.f}, qsum[4] = {0.f,0.f,0.f,0.f};
    #pragma unroll
    for (int ni = 0; ni < 4; ++ni) {
      int gn = bn + wc + ni*16 + lr;
      float bgn = bias[gn];
      #pragma unroll
      for (int mi = 0; mi < 4; ++mi)
        #pragma unroll
        for (int rr = 0; rr < 4; ++rr) {
          int gm = bm + wr + mi*16 + lq*4 + rr;
          if (gm < M) {
            u16* cp = &Cbf[(size_t)gm*HD + gn];
            float v = elu1(bf2f(*cp) + acc[mi][ni][rr] + bgn);
            *cp = f2bf(v);
            psum[ni] += v; qsum[ni] += v*v;
          }
        }
    }
    #pragma unroll
    for (int ni = 0; ni < 4; ++ni) {
      psum[ni] += __shfl_xor(psum[ni], 16, 64);
      psum[ni] += __shfl_xor(psum[ni], 32, 64);
      qsum[ni] += __shfl_xor(qsum[ni], 16, 64);
      qsum[ni] += __shfl_xor(qsum[ni], 32, 64);
    }
    if (lq == 0) {
      #pragma unroll
      for (int ni = 0; ni < 4; ++ni) {
        atomicAdd(&sdS[wc + ni*16 + lr], psum[ni]);   // exactly 2 contribs/slot
        atomicAdd(&sdQ[wc + ni*16 + lr], qsum[ni]);
      }
    }
    __syncthreads();
    if (t < BN) {
      pS[(size_t)bmi*HD + bn + t] = sdS[t];
      pQ[(size_t)bmi*HD + bn + t] = sdQ[t];
    }
  }
}

// ---------------- layer-3 linears (bf16 act) with fused GraphNorm affine ----------------
__global__ void __launch_bounds__(256) k_lin3(
    const u16* __restrict__ act, const float* __restrict__ sc, const float* __restrict__ sh,
    const float* __restrict__ W3,
    f4* __restrict__ p0, f4* __restrict__ p1, f4* __restrict__ p2, f4* __restrict__ p3) {
  int wave = threadIdx.x / 64;
  int lane = threadIdx.x % 64;
  int n = blockIdx.x*4 + wave;
  if (n >= NN) return;
  float part[4][4] = {};
  #pragma unroll
  for (int jj = 0; jj < 8; ++jj) {
    int j = lane + jj*64;
    float v = sc[j]*bf2f(act[(size_t)n*HD + j]) + sh[j];
    #pragma unroll
    for (int k = 0; k < 4; ++k) {
      f4 wv = *reinterpret_cast<const f4*>(W3 + ((size_t)k*HD + j)*4);
      #pragma unroll
      for (int c = 0; c < 4; ++c) part[k][c] += v * wv[c];
    }
  }
  #pragma unroll
  for (int k = 0; k < 4; ++k)
    #pragma unroll
    for (int c = 0; c < 4; ++c) {
      float s = part[k][c];
      #pragma unroll
      for (int off = 32; off >= 1; off >>= 1) s += __shfl_xor(s, off, 64);
      part[k][c] = s;
    }
  if (lane == 0) {
    f4 v0 = {part[0][0],part[0][1],part[0][2],part[0][3]};
    f4 v1 = {part[1][0],part[1][1],part[1][2],part[1][3]};
    f4 v2 = {part[2][0],part[2][1],part[2][2],part[2][3]};
    f4 v3 = {part[3][0],part[3][1],part[3][2],part[3][3]};
    p0[n]=v0; p1[n]=v1; p2[n]=v2; p3[n]=v3;
  }
}

// ---------------- host launch ----------------
extern "C" void kernel_launch(void* const* d_in, const int* in_sizes, int n_in,
                              void* d_out, int out_size, void* d_ws, size_t ws_size,
                              hipStream_t stream) {
  const float* x   = (const float*)d_in[0];
  const int*   ei  = (const int*)d_in[1];
  const int*   src = ei;
  const int*   dst = ei + NE;
  const float* w   = (const float*)d_in[2];
  const float* W1  = (const float*)d_in[3];
  const float* b1  = (const float*)d_in[4];
  const float* W2  = (const float*)d_in[5];
  const float* b2  = (const float*)d_in[6];
  const float* W3  = (const float*)d_in[7];
  const float* b3  = (const float*)d_in[8];
  const float* g1w = (const float*)d_in[9];
  const float* g1b = (const float*)d_in[10];
  const float* g1a = (const float*)d_in[11];
  const float* g2w = (const float*)d_in[12];
  const float* g2b = (const float*)d_in[13];
  const float* g2a = (const float*)d_in[14];

  char* p = (char*)d_ws;
  auto alloc = [&](size_t bytes) -> void* {
    void* r = (void*)p;
    p += (bytes + 255) & ~(size_t)255;
    return r;
  };
  float* deg      = (float*)alloc(NN*4);
  int*   cnt      = (int*)  alloc(NN*4);
  int*   row_ptr  = (int*)  alloc((NN+1)*4);
  int*   cursor   = (int*)  alloc(NN*4);
  int*   btot     = (int*)  alloc(256*4);
  int*   boff     = (int*)  alloc(256*4);
  edge_t* edges   = (edge_t*)alloc((size_t)NE*8);
  f4*    h1       = (f4*)   alloc((size_t)NN*16);
  f4*    h2       = (f4*)   alloc((size_t)NN*16);
  f4*    h3       = (f4*)   alloc((size_t)NN*16);
  f4*    p0       = (f4*)   alloc((size_t)NN*16);
  f4*    p1       = (f4*)   alloc((size_t)NN*16);
  f4*    p2       = (f4*)   alloc((size_t)NN*16);
  f4*    p3       = (f4*)   alloc((size_t)NN*16);
  f4*    t1       = (f4*)   alloc((size_t)NN*16);
  f4*    t2       = (f4*)   alloc((size_t)NN*16);
  float* stats    = (float*)alloc(1024*4);
  float* s1 = stats, *s2 = stats + 512;
  float* scb      = (float*)alloc(HD*4);
  float* shb      = (float*)alloc(HD*4);
  float* pS       = (float*)alloc((size_t)STATS_NB*HD*4);   // 1 MB
  float* pQ       = (float*)alloc((size_t)STATS_NB*HD*4);   // 1 MB
  u16*   W2T      = (u16*)  alloc((size_t)4*HD*HD*2);       // 2 MB
  // big buffers: 4 x 51.2 MB bf16  (~223 MB total)
  u16*   bfA      = (u16*)  alloc((size_t)NN*HD*2);   // h0, later h3
  u16*   bfB      = (u16*)  alloc((size_t)NN*HD*2);   // h1
  u16*   bfD      = (u16*)  alloc((size_t)NN*HD*2);   // h2
  u16*   bfC      = (u16*)  alloc((size_t)NN*HD*2);   // C partial then act2

  const int TPB = 256;
  int gridE = (NE + TPB - 1)/TPB;
  int gridN = (NN + TPB - 1)/TPB;
  int gridIp = (int)(((size_t)NN*HD/8 + 255)/256);
  int gridP = (NN + 3)/4;

  // CSR + norm
  hipMemsetAsync(deg, 0, NN*4, stream);
  hipMemsetAsync(cnt, 0, NN*4, stream);
  k_deg<<<gridE, TPB, 0, stream>>>(dst, w, deg, cnt);
  k_dinv<<<gridN, TPB, 0, stream>>>(deg);
  k_scanA<<<NBCHUNK, 256, 0, stream>>>(cnt, row_ptr, btot);
  k_scanB<<<1, 256, 0, stream>>>(btot, boff);
  k_scanC<<<NBCHUNK, 256, 0, stream>>>(row_ptr, boff);
  hipMemsetAsync(cursor, 0, NN*4, stream);
  k_fill<<<gridE, TPB, 0, stream>>>(src, dst, w, deg, row_ptr, cursor, edges);
  k_w2t<<<(4*HD*HD + 255)/256, 256, 0, stream>>>(W2, W2T);

  // Layer 1: hops, then fused combine+ELU+stats -> bf16 act (pre-norm) in bfA
  k_prop4<<<gridN, TPB, 0, stream>>>(row_ptr, edges, (const f4*)x, nullptr, nullptr, nullptr, h1);
  k_prop4<<<gridN, TPB, 0, stream>>>(row_ptr, edges, h1, nullptr, nullptr, nullptr, h2);
  k_prop4<<<gridN, TPB, 0, stream>>>(row_ptr, edges, h2, nullptr, nullptr, nullptr, h3);
  k_combine1s<<<STATS_NB, 256, 0, stream>>>((const f4*)x, h1, h2, h3, W1, b1, bfA, pS, pQ);
  k_reduce<<<2, 256, 0, stream>>>(pS, pQ, STATS_NB, s1, s2);
  k_affine<<<2, 256, 0, stream>>>(s1, s2, g1w, g1b, g1a, scb, shb);
  k_norm_ip<<<gridIp, 256, 0, stream>>>(bfA, scb, shb);

  // Layer 2: 4-stage GEMM||prop pipeline over h0..h3 (single stream, fat dispatches)
  //  F1: C  = h0@W0  || h1 = A h0     (bfA -> bfB)
  //  F2: C += h1@W1  || h2 = A h1     (bfB -> bfD)
  //  F3: C += h2@W2  || h3 = A h2     (bfD -> bfA; h0 dead after F1)
  //  F4: C += h3@W3, +bias +ELU +stats (GEMM only)
  k_fat<0,0,1><<<NGEMM + PROPB, 256, 0, stream>>>(
      bfA, W2T + 0*(size_t)HD*HD, bfC, nullptr, nullptr, nullptr,
      row_ptr, edges, bfA, bfB, NN);
  k_fat<1,0,1><<<NGEMM + PROPB, 256, 0, stream>>>(
      bfB, W2T + 1*(size_t)HD*HD, bfC, nullptr, nullptr, nullptr,
      row_ptr, edges, bfB, bfD, NN);
  k_fat<1,0,1><<<NGEMM + PROPB, 256, 0, stream>>>(
      bfD, W2T + 2*(size_t)HD*HD, bfC, nullptr, nullptr, nullptr,
      row_ptr, edges, bfD, bfA, NN);
  k_fat<1,1,0><<<NGEMM, 256, 0, stream>>>(
      bfA, W2T + 3*(size_t)HD*HD, bfC, b2, pS, pQ,
      row_ptr, edges, nullptr, nullptr, NN);

  // GraphNorm 2 affine from GEMM-fused partials
  k_reduce<<<2, 256, 0, stream>>>(pS, pQ, GRIDM, s1, s2);
  k_affine<<<2, 256, 0, stream>>>(s1, s2, g2w, g2b, g2a, scb, shb);

  // Layer 3: fused-norm narrow linears, then Horner with width-4 propagations
  k_lin3<<<gridP, 256, 0, stream>>>(bfC, scb, shb, W3, p0, p1, p2, p3);
  k_prop4<<<gridN, TPB, 0, stream>>>(row_ptr, edges, p3, nullptr, nullptr, nullptr, t1);
  k_prop4<<<gridN, TPB, 0, stream>>>(row_ptr, edges, p2, t1, nullptr, nullptr, t2);
  k_prop4<<<gridN, TPB, 0, stream>>>(row_ptr, edges, p1, t2, p0, b3, (f4*)d_out);
}

// Round 9
// 1086.813 us; speedup vs baseline: 1.6192x; 1.6192x over previous
//
#include <hip/hip_runtime.h>
#include <math.h>

// Problem constants
#define NN 50000      // nodes
#define NE 800000     // edges
#define HD 512        // hidden
#define GN_EPS 1e-5f
#define NBCHUNK 196   // ceil(NN/256) for scan
#define GRIDM 391     // ceil(NN/128) GEMM grid rows
#define STATS_NB 512  // combine1 stats partial blocks

typedef __attribute__((ext_vector_type(4))) float f4;
typedef __attribute__((ext_vector_type(4))) float f32x4;
typedef __attribute__((ext_vector_type(8))) short short8;
typedef unsigned short u16;
typedef __attribute__((ext_vector_type(4))) unsigned short us4;
typedef __attribute__((ext_vector_type(8))) unsigned short us8;

typedef struct { int s; float w; } edge_t;   // packed (src, norm) 8B

static __device__ __forceinline__ float elu1(float v){ return v > 0.f ? v : expm1f(v); }

static __device__ __forceinline__ float bf2f(u16 u){
  union { unsigned int i; float f; } v; v.i = ((unsigned int)u) << 16; return v.f;
}
static __device__ __forceinline__ u16 f2bf(float f){
  union { float f; unsigned int i; } v; v.f = f;
  unsigned int b = v.i;
  b += 0x7FFFu + ((b >> 16) & 1u);   // round-to-nearest-even
  return (u16)(b >> 16);
}

// A/B tile LDS address ([row][128B]): XOR 16B-slot index with (row&7); both-side swizzle.
static __device__ __forceinline__ int lds_addr(int row, int chunkByte){
  return row*128 + (chunkByte ^ ((row & 7) << 4));
}
// C tile LDS address in u16 units ([row][128 u16]): XOR 8-u16 chunk index with (row&7).
static __device__ __forceinline__ int ct_addr(int row, int col){
  return row*128 + (col ^ ((row & 7) << 3));
}

// ---------------- CSR build ----------------
__global__ void k_deg(const int* __restrict__ dst, const float* __restrict__ w,
                      float* __restrict__ deg, int* __restrict__ cnt) {
  int e = blockIdx.x*256 + threadIdx.x;
  if (e < NE) {
    int d = dst[e];
    atomicAdd(&deg[d], w[e]);
    atomicAdd(&cnt[d], 1);
  }
}

__global__ void k_dinv(float* __restrict__ deg) {
  int n = blockIdx.x*256 + threadIdx.x;
  if (n < NN) { float d = deg[n]; deg[n] = d > 0.f ? rsqrtf(d) : 0.f; }
}

// hierarchical scan: chunk-local inclusive -> chunk totals
__global__ void __launch_bounds__(256) k_scanA(const int* __restrict__ cnt,
                                               int* __restrict__ row_ptr,
                                               int* __restrict__ btot) {
  __shared__ int sh[256];
  int t = threadIdx.x, b = blockIdx.x;
  int i = b*256 + t;
  int v = (i < NN) ? cnt[i] : 0;
  sh[t] = v; __syncthreads();
  #pragma unroll
  for (int off = 1; off < 256; off <<= 1) {
    int x = (t >= off) ? sh[t-off] : 0;
    __syncthreads();
    sh[t] += x;
    __syncthreads();
  }
  if (i < NN) row_ptr[i+1] = sh[t];
  if (t == 255) btot[b] = sh[255];
}

__global__ void __launch_bounds__(256) k_scanB(const int* __restrict__ btot,
                                               int* __restrict__ boff) {
  __shared__ int sh[256];
  int t = threadIdx.x;
  int v = (t < NBCHUNK) ? btot[t] : 0;
  sh[t] = v; __syncthreads();
  #pragma unroll
  for (int off = 1; off < 256; off <<= 1) {
    int x = (t >= off) ? sh[t-off] : 0;
    __syncthreads();
    sh[t] += x;
    __syncthreads();
  }
  if (t < NBCHUNK) boff[t] = sh[t] - v;   // exclusive
}

__global__ void __launch_bounds__(256) k_scanC(int* __restrict__ row_ptr,
                                               const int* __restrict__ boff) {
  int t = threadIdx.x, b = blockIdx.x;
  int i = b*256 + t;
  if (i < NN) row_ptr[i+1] += boff[b];
  if (i == 0) row_ptr[0] = 0;
}

__global__ void k_fill(const int* __restrict__ src, const int* __restrict__ dst,
                       const float* __restrict__ w, const float* __restrict__ dinv,
                       const int* __restrict__ row_ptr, int* __restrict__ cursor,
                       edge_t* __restrict__ edges) {
  int e = blockIdx.x*256 + threadIdx.x;
  if (e < NE) {
    int s = src[e], d = dst[e];
    int pos = atomicAdd(&cursor[d], 1);
    int idx = row_ptr[d] + pos;
    edge_t ed; ed.s = s; ed.w = dinv[s] * w[e] * dinv[d];
    edges[idx] = ed;
  }
}

// ---------------- width-4 propagation (layers 1 & 3), 4-edge pipelined ----------------
__global__ void k_prop4(const int* __restrict__ row_ptr, const edge_t* __restrict__ edges,
                        const f4* __restrict__ in1, const f4* __restrict__ in2,
                        const f4* __restrict__ base, const float* __restrict__ bias,
                        f4* __restrict__ out) {
  int n = blockIdx.x*256 + threadIdx.x;
  if (n >= NN) return;
  f4 acc = {0.f,0.f,0.f,0.f};
  int e0 = row_ptr[n], e1 = row_ptr[n+1];
  int e = e0;
  if (in2) {
    for (; e + 4 <= e1; e += 4) {
      edge_t d0 = edges[e], d1 = edges[e+1], d2 = edges[e+2], d3 = edges[e+3];
      f4 a0 = in1[d0.s] + in2[d0.s];
      f4 a1 = in1[d1.s] + in2[d1.s];
      f4 a2 = in1[d2.s] + in2[d2.s];
      f4 a3 = in1[d3.s] + in2[d3.s];
      acc += d0.w*a0 + d1.w*a1 + d2.w*a2 + d3.w*a3;
    }
    for (; e < e1; ++e) {
      edge_t ed = edges[e];
      acc += ed.w * (in1[ed.s] + in2[ed.s]);
    }
  } else {
    for (; e + 4 <= e1; e += 4) {
      edge_t d0 = edges[e], d1 = edges[e+1], d2 = edges[e+2], d3 = edges[e+3];
      f4 a0 = in1[d0.s], a1 = in1[d1.s], a2 = in1[d2.s], a3 = in1[d3.s];
      acc += d0.w*a0 + d1.w*a1 + d2.w*a2 + d3.w*a3;
    }
    for (; e < e1; ++e) {
      edge_t ed = edges[e];
      acc += ed.w * in1[ed.s];
    }
  }
  if (base) acc += base[n];
  if (bias) { acc[0]+=bias[0]; acc[1]+=bias[1]; acc[2]+=bias[2]; acc[3]+=bias[3]; }
  out[n] = acc;
}

// ---------------- width-512 propagation on bf16, one wave/node, 4-edge pipelined ----------------
__global__ void __launch_bounds__(256) k_prop512_bf(
    const int* __restrict__ row_ptr, const edge_t* __restrict__ edges,
    const u16* __restrict__ in, u16* __restrict__ out) {
  int wv = threadIdx.x >> 6;
  int l  = threadIdx.x & 63;
  int n = blockIdx.x*4 + wv;
  if (n >= NN) return;
  int e0 = row_ptr[n], e1 = row_ptr[n+1];
  float acc[8] = {0.f,0.f,0.f,0.f,0.f,0.f,0.f,0.f};
  const u16* basep = in + l*8;
  int e = e0;
  for (; e + 4 <= e1; e += 4) {
    edge_t d0 = edges[e], d1 = edges[e+1], d2 = edges[e+2], d3 = edges[e+3];
    us8 v0 = *reinterpret_cast<const us8*>(basep + (size_t)d0.s*HD);
    us8 v1 = *reinterpret_cast<const us8*>(basep + (size_t)d1.s*HD);
    us8 v2 = *reinterpret_cast<const us8*>(basep + (size_t)d2.s*HD);
    us8 v3 = *reinterpret_cast<const us8*>(basep + (size_t)d3.s*HD);
    #pragma unroll
    for (int q = 0; q < 8; ++q)
      acc[q] += d0.w*bf2f(v0[q]) + d1.w*bf2f(v1[q]) + d2.w*bf2f(v2[q]) + d3.w*bf2f(v3[q]);
  }
  for (; e < e1; ++e) {
    edge_t ed = edges[e];
    us8 v = *reinterpret_cast<const us8*>(basep + (size_t)ed.s*HD);
    #pragma unroll
    for (int q = 0; q < 8; ++q) acc[q] += ed.w * bf2f(v[q]);
  }
  us8 o;
  #pragma unroll
  for (int q = 0; q < 8; ++q) o[q] = f2bf(acc[q]);
  *reinterpret_cast<us8*>(out + (size_t)n*HD + l*8) = o;
}

// ---------------- layer-1 combine fused with stats: bf16 out + column partials ----------------
__global__ void __launch_bounds__(256) k_combine1s(
    const f4* __restrict__ x, const f4* __restrict__ h1, const f4* __restrict__ h2,
    const f4* __restrict__ h3, const float* __restrict__ W1, const float* __restrict__ b1,
    u16* __restrict__ act, float* __restrict__ pS, float* __restrict__ pQ) {
  __shared__ float sdS[HD], sdQ[HD];
  int t = threadIdx.x;
  int half = t >> 7;
  int c4 = (t & 127) * 4;
  f4 wcol[16];
  #pragma unroll
  for (int kf = 0; kf < 16; ++kf)
    wcol[kf] = *reinterpret_cast<const f4*>(W1 + (size_t)kf*HD + c4);
  f4 bv = *reinterpret_cast<const f4*>(b1 + c4);
  f4 s = {0.f,0.f,0.f,0.f}, qq = {0.f,0.f,0.f,0.f};
  for (int n = blockIdx.x*2 + half; n < NN; n += gridDim.x*2) {
    f4 hv0 = x[n], hv1 = h1[n], hv2 = h2[n], hv3 = h3[n];
    f4 acc = bv;
    #pragma unroll
    for (int f = 0; f < 4; ++f) acc += hv0[f] * wcol[f];
    #pragma unroll
    for (int f = 0; f < 4; ++f) acc += hv1[f] * wcol[4+f];
    #pragma unroll
    for (int f = 0; f < 4; ++f) acc += hv2[f] * wcol[8+f];
    #pragma unroll
    for (int f = 0; f < 4; ++f) acc += hv3[f] * wcol[12+f];
    us4 o;
    #pragma unroll
    for (int e = 0; e < 4; ++e) {
      float v = elu1(acc[e]);
      s[e] += v; qq[e] += v*v;
      o[e] = f2bf(v);
    }
    *reinterpret_cast<us4*>(act + (size_t)n*HD + c4) = o;
  }
  if (half) {
    *reinterpret_cast<f4*>(&sdS[c4]) = s;
    *reinterpret_cast<f4*>(&sdQ[c4]) = qq;
  }
  __syncthreads();
  if (!half) {
    f4 ts = *reinterpret_cast<f4*>(&sdS[c4]) + s;
    f4 tq = *reinterpret_cast<f4*>(&sdQ[c4]) + qq;
    *reinterpret_cast<f4*>(&pS[(size_t)blockIdx.x*HD + c4]) = ts;
    *reinterpret_cast<f4*>(&pQ[(size_t)blockIdx.x*HD + c4]) = tq;
  }
}

// ---------------- reduce partials [nb][512] -> s1,s2 ----------------
__global__ void __launch_bounds__(256) k_reduce(
    const float* __restrict__ pS, const float* __restrict__ pQ, int nb,
    float* __restrict__ s1, float* __restrict__ s2) {
  int c = blockIdx.x*256 + threadIdx.x;
  if (c >= HD) return;
  float a = 0.f, b = 0.f;
  for (int i = 0; i < nb; ++i) {
    a += pS[(size_t)i*HD + c];
    b += pQ[(size_t)i*HD + c];
  }
  s1[c] = a; s2[c] = b;
}

// ---------------- GraphNorm scale/shift precompute: v_norm = sc*v + sh ----------------
__global__ void k_affine(const float* __restrict__ s1, const float* __restrict__ s2,
                         const float* __restrict__ gw, const float* __restrict__ gb,
                         const float* __restrict__ ga,
                         float* __restrict__ sc, float* __restrict__ sh) {
  int c = blockIdx.x*256 + threadIdx.x;
  if (c >= HD) return;
  float mu = s1[c]*(1.f/NN);
  float a  = ga[c];
  float var = s2[c]*(1.f/NN) - 2.f*a*mu*mu + a*a*mu*mu;
  float inv = rsqrtf(var + GN_EPS);
  sc[c] = gw[c]*inv;
  sh[c] = gb[c] - gw[c]*inv*a*mu;
}

// ---------------- in-place bf16 normalize with precomputed sc/sh ----------------
__global__ void k_norm_ip(u16* __restrict__ buf, const float* __restrict__ sc,
                          const float* __restrict__ sh) {
  size_t i = (size_t)blockIdx.x*256 + threadIdx.x;
  size_t total = (size_t)NN*HD/8;
  if (i >= total) return;
  int c = (int)((i*8) % HD);
  us8 v = reinterpret_cast<us8*>(buf)[i];
  #pragma unroll
  for (int e = 0; e < 8; ++e) v[e] = f2bf(bf2f(v[e])*sc[c+e] + sh[c+e]);
  reinterpret_cast<us8*>(buf)[i] = v;
}

// ---------------- W2 -> bf16 transposed: Bt[k][out][in] = bf16(W2[k][in][out]) ----------------
__global__ void k_w2t(const float* __restrict__ W2, u16* __restrict__ Bt) {
  size_t idx = (size_t)blockIdx.x*256 + threadIdx.x;
  if (idx >= (size_t)4*HD*HD) return;
  int i = (int)(idx & 511);          // in  (fastest -> coalesced write)
  int o = (int)((idx >> 9) & 511);   // out
  int k = (int)(idx >> 18);
  Bt[idx] = f2bf(W2[((size_t)k*HD + i)*HD + o]);
}

// ---------------- MFMA bf16 dual-source GEMM (K=1024): Cbf (+)= A0@B0^T + A1@B1^T ----------------
// Round-6 K-loop (reg-staged + prefetch, both-side swizzle, XCD remap) +
// NEW epilogue: C tile staged in LDS (reusing As/Bs space), coalesced us8 global I/O.
// FINAL=0: Cbf = bf16(partial).  FINAL=1: v=elu(old+acc+bias); Cbf=v; per-channel stats.
#define BM 128
#define BN 128
#define BKS 64
template<int FINAL>
__global__ void __launch_bounds__(256) k_gemm2(
    const u16* __restrict__ A0, const u16* __restrict__ A1,
    const u16* __restrict__ B0, const u16* __restrict__ B1,
    u16* __restrict__ Cbf, const float* __restrict__ bias,
    float* __restrict__ pS, float* __restrict__ pQ, int M) {
  __shared__ u16 smem[BM*BKS*2];   // 32 KB: As|Bs during K-loop, C tile in epilogue
  __shared__ float sdS[BN], sdQ[BN];
  u16* As = smem;
  u16* Bs = smem + BM*BKS;
  int t = threadIdx.x;

  // XCD-bijective remap (m204), col-fastest within consecutive ids
  int nwg = gridDim.x;            // GRIDM*4
  int q = nwg >> 3, r = nwg & 7;
  int xcd = blockIdx.x & 7, sub = blockIdx.x >> 3;
  int nid = (xcd < r ? xcd*(q+1) : r*(q+1) + (xcd - r)*q) + sub;
  int bmi = nid >> 2;             // row-panel index (0..GRIDM-1)
  int bni = nid & 3;              // col-panel index (0..3)
  int bm = bmi * BM, bn = bni * BN;

  int w  = t >> 6;
  int l  = t & 63;
  int wr = (w >> 1) * 64;
  int wc = (w & 1) * 64;
  int lr = l & 15;
  int lq = l >> 4;

  if (FINAL && t < BN) { sdS[t] = 0.f; sdQ[t] = 0.f; }

  // staging map: 4 slots/thread; slot s -> row = s>>3, 16B-chunk c8 = s&7
  size_t aoffs[4], boffs[4];
  int wb[4];
  #pragma unroll
  for (int p2 = 0; p2 < 4; ++p2) {
    int s = p2*256 + t;
    int row = s >> 3, c8 = s & 7;
    int ga = bm + row; if (ga >= M) ga = M - 1;
    aoffs[p2] = (size_t)ga*HD + c8*8;
    boffs[p2] = (size_t)(bn + row)*HD + c8*8;
    wb[p2] = lds_addr(row, c8*16);
  }

  f32x4 acc[4][4];
  #pragma unroll
  for (int i = 0; i < 4; ++i)
    #pragma unroll
    for (int j = 0; j < 4; ++j) acc[i][j] = (f32x4){0.f,0.f,0.f,0.f};

  us8 ra[4], rb[4];
  #pragma unroll
  for (int p2 = 0; p2 < 4; ++p2) {
    ra[p2] = *reinterpret_cast<const us8*>(A0 + aoffs[p2]);
    rb[p2] = *reinterpret_cast<const us8*>(B0 + boffs[p2]);
  }

  for (int k0 = 0; k0 < 2*HD; k0 += BKS) {
    __syncthreads();   // previous iteration's LDS reads complete
    #pragma unroll
    for (int p2 = 0; p2 < 4; ++p2) {
      *reinterpret_cast<us8*>((char*)As + wb[p2]) = ra[p2];
      *reinterpret_cast<us8*>((char*)Bs + wb[p2]) = rb[p2];
    }
    int k1 = k0 + BKS;
    if (k1 < 2*HD) {   // prefetch next K-tile (overlaps MFMA below)
      int off = k1 & (HD-1);
      const u16* Asrc = (k1 < HD) ? A0 : A1;
      const u16* Bsrc = (k1 < HD) ? B0 : B1;
      #pragma unroll
      for (int p2 = 0; p2 < 4; ++p2) {
        ra[p2] = *reinterpret_cast<const us8*>(Asrc + aoffs[p2] + off);
        rb[p2] = *reinterpret_cast<const us8*>(Bsrc + boffs[p2] + off);
      }
    }
    __syncthreads();   // tile ready
    #pragma unroll
    for (int ks = 0; ks < 2; ++ks) {
      short8 af[4], bfr[4];
      #pragma unroll
      for (int mi = 0; mi < 4; ++mi)
        af[mi] = *reinterpret_cast<const short8*>(
            (char*)As + lds_addr(wr + mi*16 + lr, ks*64 + lq*16));
      #pragma unroll
      for (int ni = 0; ni < 4; ++ni)
        bfr[ni] = *reinterpret_cast<const short8*>(
            (char*)Bs + lds_addr(wc + ni*16 + lr, ks*64 + lq*16));
      #pragma unroll
      for (int mi = 0; mi < 4; ++mi)
        #pragma unroll
        for (int ni = 0; ni < 4; ++ni)
          acc[mi][ni] = __builtin_amdgcn_mfma_f32_16x16x32_bf16(af[mi], bfr[ni], acc[mi][ni], 0, 0, 0);
    }
  }

  // -------- epilogue: LDS-staged coalesced C path --------
  __syncthreads();   // all ds_reads of the last tile done; smem now reusable as C tile

  int crow = t >> 1, chh = t & 1;              // cooperative row / half assignment
  if (FINAL) {
    if (bm + crow < M) {                       // coalesced load of old C into LDS
      #pragma unroll
      for (int c = 0; c < 8; ++c) {
        int col = chh*64 + c*8;
        us8 v = *reinterpret_cast<const us8*>(&Cbf[(size_t)(bm+crow)*HD + bn + col]);
        *reinterpret_cast<us8*>(&smem[ct_addr(crow, col)]) = v;
      }
    }
    __syncthreads();
  }

  float psum[4] = {0.f,0.f,0.f,0.f}, qsum[4] = {0.f,0.f,0.f,0.f};
  #pragma unroll
  for (int ni = 0; ni < 4; ++ni) {
    int coln = wc + ni*16 + lr;
    float bgn = FINAL ? bias[bn + coln] : 0.f;
    #pragma unroll
    for (int mi = 0; mi < 4; ++mi)
      #pragma unroll
      for (int rr = 0; rr < 4; ++rr) {
        int row = wr + mi*16 + lq*4 + rr;
        int ca = ct_addr(row, coln);
        if (!FINAL) {
          smem[ca] = f2bf(acc[mi][ni][rr]);
        } else if (bm + row < M) {
          float v = elu1(bf2f(smem[ca]) + acc[mi][ni][rr] + bgn);
          smem[ca] = f2bf(v);
          psum[ni] += v; qsum[ni] += v*v;
        }
      }
  }
  if (FINAL) {
    #pragma unroll
    for (int ni = 0; ni < 4; ++ni) {
      psum[ni] += __shfl_xor(psum[ni], 16, 64);
      psum[ni] += __shfl_xor(psum[ni], 32, 64);
      qsum[ni] += __shfl_xor(qsum[ni], 16, 64);
      qsum[ni] += __shfl_xor(qsum[ni], 32, 64);
    }
    if (lq == 0) {
      #pragma unroll
      for (int ni = 0; ni < 4; ++ni) {
        atomicAdd(&sdS[wc + ni*16 + lr], psum[ni]);   // exactly 2 contribs/slot
        atomicAdd(&sdQ[wc + ni*16 + lr], qsum[ni]);
      }
    }
  }
  __syncthreads();   // C tile complete (and sdS/sdQ final)

  if (bm + crow < M) {                          // coalesced store of C tile
    #pragma unroll
    for (int c = 0; c < 8; ++c) {
      int col = chh*64 + c*8;
      us8 v = *reinterpret_cast<const us8*>(&smem[ct_addr(crow, col)]);
      *reinterpret_cast<us8*>(&Cbf[(size_t)(bm+crow)*HD + bn + col]) = v;
    }
  }
  if (FINAL && t < BN) {
    pS[(size_t)bmi*HD + bn + t] = sdS[t];
    pQ[(size_t)bmi*HD + bn + t] = sdQ[t];
  }
}

// ---------------- layer-3 linears (bf16 act) with fused GraphNorm affine ----------------
__global__ void __launch_bounds__(256) k_lin3(
    const u16* __restrict__ act, const float* __restrict__ sc, const float* __restrict__ sh,
    const float* __restrict__ W3,
    f4* __restrict__ p0, f4* __restrict__ p1, f4* __restrict__ p2, f4* __restrict__ p3) {
  int wave = threadIdx.x / 64;
  int lane = threadIdx.x % 64;
  int n = blockIdx.x*4 + wave;
  if (n >= NN) return;
  float part[4][4] = {};
  #pragma unroll
  for (int jj = 0; jj < 8; ++jj) {
    int j = lane + jj*64;
    float v = sc[j]*bf2f(act[(size_t)n*HD + j]) + sh[j];
    #pragma unroll
    for (int k = 0; k < 4; ++k) {
      f4 wv = *reinterpret_cast<const f4*>(W3 + ((size_t)k*HD + j)*4);
      #pragma unroll
      for (int c = 0; c < 4; ++c) part[k][c] += v * wv[c];
    }
  }
  #pragma unroll
  for (int k = 0; k < 4; ++k)
    #pragma unroll
    for (int c = 0; c < 4; ++c) {
      float s = part[k][c];
      #pragma unroll
      for (int off = 32; off >= 1; off >>= 1) s += __shfl_xor(s, off, 64);
      part[k][c] = s;
    }
  if (lane == 0) {
    f4 v0 = {part[0][0],part[0][1],part[0][2],part[0][3]};
    f4 v1 = {part[1][0],part[1][1],part[1][2],part[1][3]};
    f4 v2 = {part[2][0],part[2][1],part[2][2],part[2][3]};
    f4 v3 = {part[3][0],part[3][1],part[3][2],part[3][3]};
    p0[n]=v0; p1[n]=v1; p2[n]=v2; p3[n]=v3;
  }
}

// ---------------- host launch ----------------
extern "C" void kernel_launch(void* const* d_in, const int* in_sizes, int n_in,
                              void* d_out, int out_size, void* d_ws, size_t ws_size,
                              hipStream_t stream) {
  const float* x   = (const float*)d_in[0];
  const int*   ei  = (const int*)d_in[1];
  const int*   src = ei;
  const int*   dst = ei + NE;
  const float* w   = (const float*)d_in[2];
  const float* W1  = (const float*)d_in[3];
  const float* b1  = (const float*)d_in[4];
  const float* W2  = (const float*)d_in[5];
  const float* b2  = (const float*)d_in[6];
  const float* W3  = (const float*)d_in[7];
  const float* b3  = (const float*)d_in[8];
  const float* g1w = (const float*)d_in[9];
  const float* g1b = (const float*)d_in[10];
  const float* g1a = (const float*)d_in[11];
  const float* g2w = (const float*)d_in[12];
  const float* g2b = (const float*)d_in[13];
  const float* g2a = (const float*)d_in[14];

  char* p = (char*)d_ws;
  auto alloc = [&](size_t bytes) -> void* {
    void* r = (void*)p;
    p += (bytes + 255) & ~(size_t)255;
    return r;
  };
  float* deg      = (float*)alloc(NN*4);
  int*   cnt      = (int*)  alloc(NN*4);
  int*   row_ptr  = (int*)  alloc((NN+1)*4);
  int*   cursor   = (int*)  alloc(NN*4);
  int*   btot     = (int*)  alloc(256*4);
  int*   boff     = (int*)  alloc(256*4);
  edge_t* edges   = (edge_t*)alloc((size_t)NE*8);
  f4*    h1       = (f4*)   alloc((size_t)NN*16);
  f4*    h2       = (f4*)   alloc((size_t)NN*16);
  f4*    h3       = (f4*)   alloc((size_t)NN*16);
  f4*    p0       = (f4*)   alloc((size_t)NN*16);
  f4*    p1       = (f4*)   alloc((size_t)NN*16);
  f4*    p2       = (f4*)   alloc((size_t)NN*16);
  f4*    p3       = (f4*)   alloc((size_t)NN*16);
  f4*    t1       = (f4*)   alloc((size_t)NN*16);
  f4*    t2       = (f4*)   alloc((size_t)NN*16);
  float* stats    = (float*)alloc(1024*4);
  float* s1 = stats, *s2 = stats + 512;
  float* scb      = (float*)alloc(HD*4);
  float* shb      = (float*)alloc(HD*4);
  float* pS       = (float*)alloc((size_t)STATS_NB*HD*4);   // 1 MB
  float* pQ       = (float*)alloc((size_t)STATS_NB*HD*4);   // 1 MB
  u16*   W2T      = (u16*)  alloc((size_t)4*HD*HD*2);       // 2 MB
  // big buffers: 3 x 51.2 MB bf16  (~175 MB total)
  u16*   bfA      = (u16*)  alloc((size_t)NN*HD*2);
  u16*   bfB      = (u16*)  alloc((size_t)NN*HD*2);
  u16*   bfC      = (u16*)  alloc((size_t)NN*HD*2);   // C partial then act2

  const int TPB = 256;
  int gridE = (NE + TPB - 1)/TPB;
  int gridN = (NN + TPB - 1)/TPB;
  int gridIp = (int)(((size_t)NN*HD/8 + 255)/256);
  int gridP = (NN + 3)/4;

  // CSR + norm
  hipMemsetAsync(deg, 0, NN*4, stream);
  hipMemsetAsync(cnt, 0, NN*4, stream);
  k_deg<<<gridE, TPB, 0, stream>>>(dst, w, deg, cnt);
  k_dinv<<<gridN, TPB, 0, stream>>>(deg);
  k_scanA<<<NBCHUNK, 256, 0, stream>>>(cnt, row_ptr, btot);
  k_scanB<<<1, 256, 0, stream>>>(btot, boff);
  k_scanC<<<NBCHUNK, 256, 0, stream>>>(row_ptr, boff);
  hipMemsetAsync(cursor, 0, NN*4, stream);
  k_fill<<<gridE, TPB, 0, stream>>>(src, dst, w, deg, row_ptr, cursor, edges);
  k_w2t<<<(4*HD*HD + 255)/256, 256, 0, stream>>>(W2, W2T);

  // Layer 1: hops, then fused combine+ELU+stats -> bf16 act (pre-norm) in bfA
  k_prop4<<<gridN, TPB, 0, stream>>>(row_ptr, edges, (const f4*)x, nullptr, nullptr, nullptr, h1);
  k_prop4<<<gridN, TPB, 0, stream>>>(row_ptr, edges, h1, nullptr, nullptr, nullptr, h2);
  k_prop4<<<gridN, TPB, 0, stream>>>(row_ptr, edges, h2, nullptr, nullptr, nullptr, h3);
  k_combine1s<<<STATS_NB, 256, 0, stream>>>((const f4*)x, h1, h2, h3, W1, b1, bfA, pS, pQ);
  k_reduce<<<2, 256, 0, stream>>>(pS, pQ, STATS_NB, s1, s2);
  k_affine<<<2, 256, 0, stream>>>(s1, s2, g1w, g1b, g1a, scb, shb);
  k_norm_ip<<<gridIp, 256, 0, stream>>>(bfA, scb, shb);

  // Layer 2: h0=bfA, h1=prop(h0)=bfB -> GEMM1 writes Cbf (bf16 partial);
  //          h2=prop(h1)=bfA, h3=prop(h2)=bfB -> GEMM2 RMW + bias+ELU+stats
  k_prop512_bf<<<gridP, 256, 0, stream>>>(row_ptr, edges, bfA, bfB);
  k_gemm2<0><<<GRIDM*4, 256, 0, stream>>>(bfA, bfB, W2T, W2T + (size_t)HD*HD,
                                          bfC, nullptr, nullptr, nullptr, NN);
  k_prop512_bf<<<gridP, 256, 0, stream>>>(row_ptr, edges, bfB, bfA);
  k_prop512_bf<<<gridP, 256, 0, stream>>>(row_ptr, edges, bfA, bfB);
  k_gemm2<1><<<GRIDM*4, 256, 0, stream>>>(bfA, bfB, W2T + 2*(size_t)HD*HD, W2T + 3*(size_t)HD*HD,
                                          bfC, b2, pS, pQ, NN);

  // GraphNorm 2 affine from GEMM-fused partials
  k_reduce<<<2, 256, 0, stream>>>(pS, pQ, GRIDM, s1, s2);
  k_affine<<<2, 256, 0, stream>>>(s1, s2, g2w, g2b, g2a, scb, shb);

  // Layer 3: fused-norm narrow linears, then Horner with width-4 propagations
  k_lin3<<<gridP, 256, 0, stream>>>(bfC, scb, shb, W3, p0, p1, p2, p3);
  k_prop4<<<gridN, TPB, 0, stream>>>(row_ptr, edges, p3, nullptr, nullptr, nullptr, t1);
  k_prop4<<<gridN, TPB, 0, stream>>>(row_ptr, edges, p2, t1, nullptr, nullptr, t2);
  k_prop4<<<gridN, TPB, 0, stream>>>(row_ptr, edges, p1, t2, p0, b3, (f4*)d_out);
}